// Round 9
// baseline (298.861 us; speedup 1.0000x reference)
//
#include <hip/hip_runtime.h>

#define T_LEN 1024

typedef _Float16 f16x8 __attribute__((ext_vector_type(8)));
typedef __fp16   fp16x2 __attribute__((ext_vector_type(2)));
typedef float    f32x4 __attribute__((ext_vector_type(4)));

// Full-rate reciprocal: bit-trick seed + 2 Newton iterations (rel err ~6e-6).
// 5 scalar ops = 10 issue-cyc/wave64 vs v_rcp_f32's 16. Valid for d in [2^-125, 2^125];
// here d = exp2(t)+1 is in [1, ~5405].
__device__ __forceinline__ float rcp_sw(float d) {
    float r = __builtin_bit_cast(float, 0x7EF311C3u - __builtin_bit_cast(unsigned, d));
    r = r * fmaf(-d, r, 2.0f);
    r = r * fmaf(-d, r, 2.0f);
    return r;
}

// One wave (64 threads) per block; block owns 16 batch rows for all T steps.
// Recurrence in "r-space": h = 1 - 2r, r = 1/(exp2(t)+1), t = K*v, K = 2*log2(e).
// Substituting h into v = x*Wih + b + W_hh h:
//   t[c] = K*(x*Wih[c] + b[c] + rowsum(W_hh[c,:])) + sum_k (-2K*W_hh[c,k]) * r[k]
// so A-frag = -2K*W_hh (f16) and r recirculates directly as the B-fragment.
//   A-frag: A[m=lane&15][k=quad*8+j] = -2K*Whh[sigma(m)][k]
//   B-frag: B[k=quad*8+j][n=lane&15] = r[row n][k]
//   C-frag: col n=lane&15 (batch row), row m=quad*4+reg; sigma0(m)=8*(m>>2)+(m&3),
//   sigma1=sigma0+4 ==> lane's C outputs are exactly its own B slots next step.
// tanh pipeline per step: 8x v_exp_f32 (HW, 16cyc) + 8 add + software rcp (full rate)
// + 4x v_cvt_pkrtz. Trans-pipe ops cut 16 -> 8 per step vs r7/r8.
__global__ __launch_bounds__(64) void rnn_fused(
    const float* __restrict__ x,      // [B, T]
    const float* __restrict__ W_ih,   // [32,1]
    const float* __restrict__ W_hh,   // [32,32]
    const float* __restrict__ b_ih,   // [32]
    const float* __restrict__ b_hh,   // [32]
    const float* __restrict__ fc_w,   // [1,32]
    const float* __restrict__ fc_b,   // [1]
    float* __restrict__ out)          // [B]
{
    const int lane = threadIdx.x;
    const int n = lane & 15;   // batch row within tile (B-frag col / C col)
    const int q = lane >> 4;   // quad index

    const float K = 2.88539008177792681472f;   // 2*log2(e)

    // A fragments: -2K * W_hh rows (permuted by sigma), f16.
    const int c0row = 8 * (n >> 2) + (n & 3);
    const int c1row = c0row + 4;
    f16x8 a0, a1;
#pragma unroll
    for (int j = 0; j < 8; ++j) {
        a0[j] = (_Float16)(-2.0f * K * W_hh[c0row * 32 + q * 8 + j]);
        a1[j] = (_Float16)(-2.0f * K * W_hh[c1row * 32 + q * 8 + j]);
    }

    // This lane produces h-columns c = 8q + i (i = 0..7).
    // bias' = K*(b_ih + b_hh + rowsum(W_hh[c,:]))  (r-space fold)
    float wih[8], bias[8];
#pragma unroll
    for (int i = 0; i < 8; ++i) {
        int c = 8 * q + i;
        float rs = 0.0f;
        for (int k = 0; k < 32; ++k) rs += W_hh[c * 32 + k];
        wih[i]  = K * W_ih[c];
        bias[i] = K * (b_ih[c] + b_hh[c] + rs);
    }

    const float* xrow = x + (size_t)(blockIdx.x * 16 + n) * T_LEN;
    float4 xa = *(const float4*)xrow;   // t = 0..3 (4 lanes/row redundant -> broadcast)

    // B fragment holds r; h=0 <=> r=0.5
    f16x8 hb;
#pragma unroll
    for (int i = 0; i < 8; ++i) hb[i] = (_Float16)0.5f;

    for (int t4 = 0; t4 < T_LEN / 4; ++t4) {
        const int nt4 = (t4 < T_LEN / 4 - 1) ? t4 + 1 : t4;   // prefetch next x chunk
        float4 xn = *(const float4*)(xrow + (size_t)nt4 * 4);
#pragma unroll
        for (int p = 0; p < 4; ++p) {
            const float xt = (p == 0) ? xa.x : (p == 1) ? xa.y : (p == 2) ? xa.z : xa.w;
            f32x4 acc0, acc1;
#pragma unroll
            for (int i = 0; i < 4; ++i) {
                acc0[i] = fmaf(xt, wih[i],     bias[i]);   // C-init = K*(x*Wih + b + rowsum)
                acc1[i] = fmaf(xt, wih[4 + i], bias[4 + i]);
            }
            acc0 = __builtin_amdgcn_mfma_f32_16x16x32_f16(a0, hb, acc0, 0, 0, 0);
            acc1 = __builtin_amdgcn_mfma_f32_16x16x32_f16(a1, hb, acc1, 0, 0, 0);

            // 8 HW exps stream back-to-back through the trans pipe
            float e0 = __builtin_amdgcn_exp2f(acc0[0]);
            float e1 = __builtin_amdgcn_exp2f(acc0[1]);
            float e2 = __builtin_amdgcn_exp2f(acc0[2]);
            float e3 = __builtin_amdgcn_exp2f(acc0[3]);
            float e4 = __builtin_amdgcn_exp2f(acc1[0]);
            float e5 = __builtin_amdgcn_exp2f(acc1[1]);
            float e6 = __builtin_amdgcn_exp2f(acc1[2]);
            float e7 = __builtin_amdgcn_exp2f(acc1[3]);
            // r = 1/(E+1) at full VALU rate
            float r0 = rcp_sw(e0 + 1.0f);
            float r1 = rcp_sw(e1 + 1.0f);
            float r2 = rcp_sw(e2 + 1.0f);
            float r3 = rcp_sw(e3 + 1.0f);
            float r4 = rcp_sw(e4 + 1.0f);
            float r5 = rcp_sw(e5 + 1.0f);
            float r6 = rcp_sw(e6 + 1.0f);
            float r7 = rcp_sw(e7 + 1.0f);

            // pack r pairs: 4 x v_cvt_pkrtz_f16_f32
            struct H4 { fp16x2 p[4]; } hh;
            hh.p[0] = __builtin_amdgcn_cvt_pkrtz(r0, r1);
            hh.p[1] = __builtin_amdgcn_cvt_pkrtz(r2, r3);
            hh.p[2] = __builtin_amdgcn_cvt_pkrtz(r4, r5);
            hh.p[3] = __builtin_amdgcn_cvt_pkrtz(r6, r7);
            hb = __builtin_bit_cast(f16x8, hh);
        }
        xa = xn;
    }

    // Head: h = 1 - 2r; out[row] = sum_c h[c] * fc_w[c] + fc_b
    float part = 0.0f;
#pragma unroll
    for (int i = 0; i < 8; ++i) {
        float h = fmaf(-2.0f, (float)hb[i], 1.0f);
        part = fmaf(h, fc_w[8 * q + i], part);
    }
    part += __shfl_xor(part, 16);
    part += __shfl_xor(part, 32);
    if (q == 0) out[blockIdx.x * 16 + n] = part + fc_b[0];
}

extern "C" void kernel_launch(void* const* d_in, const int* in_sizes, int n_in,
                              void* d_out, int out_size, void* d_ws, size_t ws_size,
                              hipStream_t stream) {
    const float* x    = (const float*)d_in[0];
    const float* W_ih = (const float*)d_in[1];
    const float* W_hh = (const float*)d_in[2];
    const float* b_ih = (const float*)d_in[3];
    const float* b_hh = (const float*)d_in[4];
    const float* fc_w = (const float*)d_in[5];
    const float* fc_b = (const float*)d_in[6];
    float* out = (float*)d_out;

    const int B = in_sizes[0] / T_LEN;   // 16384
    rnn_fused<<<B / 16, 64, 0, stream>>>(x, W_ih, W_hh, b_ih, b_hh, fc_w, fc_b, out);
}

// Round 10
// 254.983 us; speedup vs baseline: 1.1721x; 1.1721x over previous
//
#include <hip/hip_runtime.h>

#define T_LEN 1024

typedef _Float16 f16x8 __attribute__((ext_vector_type(8)));
typedef __fp16   fp16x2 __attribute__((ext_vector_type(2)));
typedef float    f32x4 __attribute__((ext_vector_type(4)));

// One wave (64 threads) per block; block owns 16 batch rows for all T steps.
// Recurrence in "r-space": h = 1 - 2r, r = 1/(exp2(t)+1), t = K*v, K = 2*log2(e).
// Substituting h into v = x*Wih + b + W_hh h:
//   t[c] = K*(x*Wih[c] + b[c] + rowsum(W_hh[c,:])) + sum_k (-2K*W_hh[c,k]) * r[k]
// so A-frag = -2K*W_hh (f16) and r recirculates directly as the B-fragment.
//   A-frag: A[m=lane&15][k=quad*8+j] = -2K*Whh[sigma(m)][k]
//   B-frag: B[k=quad*8+j][n=lane&15] = r[row n][k]
//   C-frag: col n=lane&15 (batch row), row m=quad*4+reg; sigma0(m)=8*(m>>2)+(m&3),
//   sigma1=sigma0+4 ==> lane's C outputs are exactly its own B slots next step.
//
// Per-step pipeline (all hardware, minimal chain):
//   MFMA -> v_exp_f32(acc) -> +1 -> v_rcp_f32 -> v_cvt_pkrtz -> B-frag.
// HW trans kept deliberately: r4/r5/r6/r9 all showed software replacements add
// net issue cycles (trans ops issue cheaply; the pipe grinds in background).
__global__ __launch_bounds__(64) void rnn_fused(
    const float* __restrict__ x,      // [B, T]
    const float* __restrict__ W_ih,   // [32,1]
    const float* __restrict__ W_hh,   // [32,32]
    const float* __restrict__ b_ih,   // [32]
    const float* __restrict__ b_hh,   // [32]
    const float* __restrict__ fc_w,   // [1,32]
    const float* __restrict__ fc_b,   // [1]
    float* __restrict__ out)          // [B]
{
    const int lane = threadIdx.x;
    const int n = lane & 15;   // batch row within tile (B-frag col / C col)
    const int q = lane >> 4;   // quad index

    const float K = 2.88539008177792681472f;   // 2*log2(e)

    // A fragments: -2K * W_hh rows (permuted by sigma), f16.
    const int c0row = 8 * (n >> 2) + (n & 3);
    const int c1row = c0row + 4;
    f16x8 a0, a1;
#pragma unroll
    for (int j = 0; j < 8; ++j) {
        a0[j] = (_Float16)(-2.0f * K * W_hh[c0row * 32 + q * 8 + j]);
        a1[j] = (_Float16)(-2.0f * K * W_hh[c1row * 32 + q * 8 + j]);
    }

    // This lane produces h-columns c = 8q + i (i = 0..7).
    // bias' = K*(b_ih + b_hh + rowsum(W_hh[c,:]))  (r-space fold)
    float wih[8], bias[8];
#pragma unroll
    for (int i = 0; i < 8; ++i) {
        int c = 8 * q + i;
        float rs = 0.0f;
        for (int k = 0; k < 32; ++k) rs += W_hh[c * 32 + k];
        wih[i]  = K * W_ih[c];
        bias[i] = K * (b_ih[c] + b_hh[c] + rs);
    }

    const float* xrow = x + (size_t)(blockIdx.x * 16 + n) * T_LEN;
    float4 xa = *(const float4*)xrow;   // t = 0..3 (4 lanes/row redundant -> broadcast)

    // B fragment holds r; h=0 <=> r=0.5
    f16x8 hb;
#pragma unroll
    for (int i = 0; i < 8; ++i) hb[i] = (_Float16)0.5f;

    for (int t4 = 0; t4 < T_LEN / 4; ++t4) {
        const int nt4 = (t4 < T_LEN / 4 - 1) ? t4 + 1 : t4;   // prefetch next x chunk
        float4 xn = *(const float4*)(xrow + (size_t)nt4 * 4);
#pragma unroll
        for (int p = 0; p < 4; ++p) {
            const float xt = (p == 0) ? xa.x : (p == 1) ? xa.y : (p == 2) ? xa.z : xa.w;
            f32x4 acc0, acc1;
#pragma unroll
            for (int i = 0; i < 4; ++i) {
                acc0[i] = fmaf(xt, wih[i],     bias[i]);   // C-init = K*(x*Wih + b + rowsum)
                acc1[i] = fmaf(xt, wih[4 + i], bias[4 + i]);
            }
            acc0 = __builtin_amdgcn_mfma_f32_16x16x32_f16(a0, hb, acc0, 0, 0, 0);
            acc1 = __builtin_amdgcn_mfma_f32_16x16x32_f16(a1, hb, acc1, 0, 0, 0);

            // 8 HW exps stream through the trans pipe; adds interleave; 8 HW rcps.
            float e0 = __builtin_amdgcn_exp2f(acc0[0]);
            float e1 = __builtin_amdgcn_exp2f(acc0[1]);
            float e2 = __builtin_amdgcn_exp2f(acc0[2]);
            float e3 = __builtin_amdgcn_exp2f(acc0[3]);
            float e4 = __builtin_amdgcn_exp2f(acc1[0]);
            float e5 = __builtin_amdgcn_exp2f(acc1[1]);
            float e6 = __builtin_amdgcn_exp2f(acc1[2]);
            float e7 = __builtin_amdgcn_exp2f(acc1[3]);
            float r0 = __builtin_amdgcn_rcpf(e0 + 1.0f);
            float r1 = __builtin_amdgcn_rcpf(e1 + 1.0f);
            float r2 = __builtin_amdgcn_rcpf(e2 + 1.0f);
            float r3 = __builtin_amdgcn_rcpf(e3 + 1.0f);
            float r4 = __builtin_amdgcn_rcpf(e4 + 1.0f);
            float r5 = __builtin_amdgcn_rcpf(e5 + 1.0f);
            float r6 = __builtin_amdgcn_rcpf(e6 + 1.0f);
            float r7 = __builtin_amdgcn_rcpf(e7 + 1.0f);

            // pack r pairs directly: 4 x v_cvt_pkrtz_f16_f32 (no final fma — r-space)
            struct H4 { fp16x2 p[4]; } hh;
            hh.p[0] = __builtin_amdgcn_cvt_pkrtz(r0, r1);
            hh.p[1] = __builtin_amdgcn_cvt_pkrtz(r2, r3);
            hh.p[2] = __builtin_amdgcn_cvt_pkrtz(r4, r5);
            hh.p[3] = __builtin_amdgcn_cvt_pkrtz(r6, r7);
            hb = __builtin_bit_cast(f16x8, hh);
        }
        xa = xn;
    }

    // Head: h = 1 - 2r; out[row] = sum_c h[c] * fc_w[c] + fc_b
    float part = 0.0f;
#pragma unroll
    for (int i = 0; i < 8; ++i) {
        float h = fmaf(-2.0f, (float)hb[i], 1.0f);
        part = fmaf(h, fc_w[8 * q + i], part);
    }
    part += __shfl_xor(part, 16);
    part += __shfl_xor(part, 32);
    if (q == 0) out[blockIdx.x * 16 + n] = part + fc_b[0];
}

extern "C" void kernel_launch(void* const* d_in, const int* in_sizes, int n_in,
                              void* d_out, int out_size, void* d_ws, size_t ws_size,
                              hipStream_t stream) {
    const float* x    = (const float*)d_in[0];
    const float* W_ih = (const float*)d_in[1];
    const float* W_hh = (const float*)d_in[2];
    const float* b_ih = (const float*)d_in[3];
    const float* b_hh = (const float*)d_in[4];
    const float* fc_w = (const float*)d_in[5];
    const float* fc_b = (const float*)d_in[6];
    float* out = (float*)d_out;

    const int B = in_sizes[0] / T_LEN;   // 16384
    rnn_fused<<<B / 16, 64, 0, stream>>>(x, W_ih, W_hh, b_ih, b_hh, fc_w, fc_b, out);
}